// Round 7
// baseline (313.758 us; speedup 1.0000x reference)
//
#include <hip/hip_runtime.h>

// LCT FK-migration: 3D FFT(512,256,256) -> Stolt trilinear resample -> 3D IFFT -> |.|^2
// Single 256 MiB workspace buffer V = [512][256][256] cpx, flat (z<<16)+(y<<8)+x.
// x/y spectra stored FFTSHIFTED with the half-pixel Stolt x/y blurs folded into the
// forward x/y FFT stores (ix = xs-0.5, iy = ys-0.5 exactly => fx=fy=0.5 fixed blur).
// Z-STAGE IS FULLY FUSED (k_fftz_pair): dest column (y,x) gathers from source column
// ((y+128)&255,(x+128)&255) — an involution pairing columns. Each block processes a
// pair {A,B}: fwd 512-pt FFT of both in LDS, z-only Stolt gather of each from the
// OTHER buffer (LDS reads, digit-reversal folded into the gather index), inverse FFT,
// write planes 0..255. No z-spectrum ever touches HBM.
// Then inverse y (crop y<128) and inverse x fused with |.|^2 (crop x<128).

typedef float2 cpx;

__device__ float2 g_tw[512];   // exp(-2*pi*i*k/512), k in [0,512)

__device__ __forceinline__ cpx cadd(cpx a, cpx b){ return make_float2(a.x+b.x, a.y+b.y); }
__device__ __forceinline__ cpx csub(cpx a, cpx b){ return make_float2(a.x-b.x, a.y-b.y); }
__device__ __forceinline__ cpx cmul(cpx a, cpx b){ return make_float2(a.x*b.x - a.y*b.y, a.x*b.y + a.y*b.x); }

// ---------------- twiddle table (double-computed for accuracy) ----------------
__global__ void k_tw(){
    int j = threadIdx.x;                        // 512 threads
    double a = -2.0*3.14159265358979323846*(double)j/512.0;
    g_tw[j] = make_float2((float)cos(a), (float)sin(a));
}

template<bool INV>
__device__ __forceinline__ cpx twmul(cpx a, int k){
    cpx w = g_tw[k & 511];
    if (INV) w.y = -w.y;
    return cmul(a, w);
}

// ---------------- radix-4 DIF butterfly (in-register) ----------------
template<bool INV>
__device__ __forceinline__ void dft4(cpx* x){
    cpx e0 = cadd(x[0], x[2]), e1 = csub(x[0], x[2]);
    cpx o0 = cadd(x[1], x[3]), o1 = csub(x[1], x[3]);
    x[0] = cadd(e0, o0);
    x[2] = csub(e0, o0);
    if (!INV){ x[1] = make_float2(e1.x + o1.y, e1.y - o1.x);
               x[3] = make_float2(e1.x - o1.y, e1.y + o1.x); }
    else     { x[1] = make_float2(e1.x - o1.y, e1.y + o1.x);
               x[3] = make_float2(e1.x + o1.y, e1.y - o1.x); }
}

// ---------------- radix-8 DIF butterfly (in-register) ----------------
template<bool INV>
__device__ __forceinline__ void dft8(cpx* x){
    const float s = 0.70710678118654752440f;
    cpx e0 = cadd(x[0], x[4]), e2 = csub(x[0], x[4]);
    cpx e1 = cadd(x[2], x[6]), e3 = csub(x[2], x[6]);
    cpx E0 = cadd(e0, e1), E2 = csub(e0, e1);
    cpx E1, E3;
    if (!INV){ E1 = make_float2(e2.x + e3.y, e2.y - e3.x);
               E3 = make_float2(e2.x - e3.y, e2.y + e3.x); }
    else     { E1 = make_float2(e2.x - e3.y, e2.y + e3.x);
               E3 = make_float2(e2.x + e3.y, e2.y - e3.x); }
    cpx o0 = cadd(x[1], x[5]), o2 = csub(x[1], x[5]);
    cpx o1 = cadd(x[3], x[7]), o3 = csub(x[3], x[7]);
    cpx O0 = cadd(o0, o1), O2 = csub(o0, o1);
    cpx O1, O3;
    if (!INV){ O1 = make_float2(o2.x + o3.y, o2.y - o3.x);
               O3 = make_float2(o2.x - o3.y, o2.y + o3.x); }
    else     { O1 = make_float2(o2.x - o3.y, o2.y + o3.x);
               O3 = make_float2(o2.x + o3.y, o2.y - o3.x); }
    cpx W1, W2, W3;
    if (!INV){
        W1 = make_float2(s*(O1.x + O1.y), s*(O1.y - O1.x));
        W2 = make_float2(O2.y, -O2.x);
        W3 = make_float2(s*(O3.y - O3.x), -s*(O3.x + O3.y));
    } else {
        W1 = make_float2(s*(O1.x - O1.y), s*(O1.x + O1.y));
        W2 = make_float2(-O2.y, O2.x);
        W3 = make_float2(-s*(O3.x + O3.y), s*(O3.x - O3.y));
    }
    x[0] = cadd(E0, O0); x[4] = csub(E0, O0);
    x[1] = cadd(E1, W1); x[5] = csub(E1, W1);
    x[2] = cadd(E2, W2); x[6] = csub(E2, W2);
    x[3] = cadd(E3, W3); x[7] = csub(E3, W3);
}

// ---------------- one radix-8 DIF stage of a 512-pt FFT in LDS (layout s[e*16+c]) ----------------
template<bool INV, int STAGE>
__device__ __forceinline__ void zstage(cpx* s, int c, int idx){
    cpx x[8];
    if (STAGE == 0){
        int j = idx;                             // stride 64, tw W_512^{j*r}
        #pragma unroll
        for (int t = 0; t < 8; ++t) x[t] = s[(j + (t << 6))*16 + c];
        dft8<INV>(x);
        #pragma unroll
        for (int r = 1; r < 8; ++r) x[r] = twmul<INV>(x[r], j*r);
        #pragma unroll
        for (int r = 0; r < 8; ++r) s[(j + (r << 6))*16 + c] = x[r];
    } else if (STAGE == 1){
        int j = idx & 7, g = (idx >> 3) << 6;    // stride 8, tw W_512^{8*j*r}
        #pragma unroll
        for (int t = 0; t < 8; ++t) x[t] = s[(g + j + (t << 3))*16 + c];
        dft8<INV>(x);
        #pragma unroll
        for (int r = 1; r < 8; ++r) x[r] = twmul<INV>(x[r], 8*j*r);
        #pragma unroll
        for (int r = 0; r < 8; ++r) s[(g + j + (r << 3))*16 + c] = x[r];
    } else {
        int g = idx << 3;                        // stride 1, no twiddle
        #pragma unroll
        for (int t = 0; t < 8; ++t) x[t] = s[(g + t)*16 + c];
        dft8<INV>(x);
        #pragma unroll
        for (int r = 0; r < 8; ++r) s[(g + r)*16 + c] = x[r];
    }
}

// ---------------- z-only Stolt gather from an in-LDS fwd spectrum (digit-reversed order) ----------------
// buf holds bins b in [0,512) at position rev8(b); gather needs bins z0-256, z1-256 (in [0,255]).
__device__ __forceinline__ cpx zgather(const cpx* __restrict__ buf, int zd, float rxy, int c){
    if (!zd) return make_float2(0.0f, 0.0f);     // t[:, :M+1] = 0 plane
    float gz = (float)zd*(1.0f/256.0f);
    float gzn = sqrtf(rxy + gz*gz);
    float iz = ((gzn + 1.0f)*512.0f - 1.0f)*0.5f;
    float fiz = floorf(iz);
    int iz0 = (int)fiz;                          // in [256, ~536)
    float fz = iz - fiz;
    float sc = gz/(gzn + 1e-8f);
    int b0 = (iz0 < 511 ? iz0 : 511) - 256;
    int b1 = ((iz0 + 1) < 511 ? (iz0 + 1) : 511) - 256;
    float w0 = (iz0     <= 511) ? (1.0f - fz)*sc : 0.0f;
    float w1 = (iz0 + 1 <= 511) ? fz*sc : 0.0f;
    int p0 = ((b0 & 7) << 6) | (b0 & 56) | (b0 >> 6);
    int p1 = ((b1 & 7) << 6) | (b1 & 56) | (b1 >> 6);
    cpx a = buf[p0*16 + c];
    cpx b = buf[p1*16 + c];
    return make_float2(a.x*w0 + b.x*w1, a.y*w0 + b.y*w1);
}

// ---------------- in-LDS radix-2 FFT, layout s[line][elem], 2 lines of 256 ----------------
template<bool INV>
__device__ __forceinline__ void fft_rows2(cpx* s, const cpx* ltw, int tid){
    const int L2LEN = 8, LEN = 256;
    #pragma unroll
    for (int st = 0; st < L2LEN; ++st){
        int lh = L2LEN - 1 - st;
        int half = 1 << lh;
        int tws = 512 >> (L2LEN - st);
        int l  = tid >> (L2LEN - 1);
        int bf = tid & ((LEN/2) - 1);
        int j  = bf & (half - 1);
        int i0 = ((bf >> lh) << (lh + 1)) | j;
        cpx u = s[l*LEN + i0], v = s[l*LEN + i0 + half];
        cpx w = ltw[j*tws];
        if (INV) w.y = -w.y;
        s[l*LEN + i0]        = cadd(u, v);
        s[l*LEN + i0 + half] = cmul(csub(u, v), w);
        __syncthreads();
    }
    for (int i = tid; i < 2*LEN; i += 256){     // bit-reversal -> natural order
        int l = i >> L2LEN, k = i & (LEN - 1);
        int r = __brev((unsigned)k) >> (32 - L2LEN);
        if (r > k){ cpx a = s[l*LEN + k]; s[l*LEN + k] = s[l*LEN + r]; s[l*LEN + r] = a; }
    }
    __syncthreads();
}

// ---------------- forward x-FFT fused with fill; store x-fftshifted AND x-half-blurred ----------------
__global__ __launch_bounds__(256) void k_fft_x_fill(const float* __restrict__ feat, cpx* __restrict__ V){
    __shared__ cpx s[2*256];
    __shared__ cpx ltw[256];
    int tid = threadIdx.x;
    ltw[tid] = g_tw[tid];
    int line0 = blockIdx.x << 1;                 // line = z*128 + y, z<256, y<128
    {
        int l = tid >> 7, e = tid & 127;
        int line = line0 + l;
        int z = line >> 7;
        float g = (float)z*(1.0f/255.0f);
        float v = feat[(line << 7) + e]*g*g;     // feat[z][y][x]
        v = v > 0.0f ? sqrtf(v) : 0.0f;
        s[l*256 + e]       = make_float2(v, 0.0f);
        s[l*256 + e + 128] = make_float2(0.0f, 0.0f);
    }
    __syncthreads();
    fft_rows2<false>(s, ltw, tid);
    {   // store blurred, float4 (positions 2f, 2f+1) per thread
        int l = tid >> 7, f = tid & 127;
        int line = line0 + l;
        int base = ((line >> 7) << 16) + ((line & 127) << 8);
        const float4* srow = (const float4*)(s + l*256);
        float4 A = srow[f ^ 64];                 // F_s[2f], F_s[2f+1]
        float4 B = make_float4(0.0f, 0.0f, 0.0f, 0.0f);
        if (f) B = srow[(f - 1) ^ 64];           // .zw = F_s[2f-1]
        float4 o;
        o.x = 0.5f*(B.z + A.x); o.y = 0.5f*(B.w + A.y);
        o.z = 0.5f*(A.x + A.z); o.w = 0.5f*(A.y + A.w);
        ((float4*)(V + base))[f] = o;
    }
}

// ---------------- final inverse x-FFT fused with |.|^2, crop x<128 ----------------
__global__ __launch_bounds__(256) void k_fft_x_inv_mag(const cpx* __restrict__ W,
                                                       float* __restrict__ out){
    __shared__ cpx s[2*256];
    __shared__ cpx ltw[256];
    int tid = threadIdx.x;
    ltw[tid] = g_tw[tid];
    int line0 = blockIdx.x << 1;
    {   // load 2 cpx per thread
        int l = tid >> 7, f4c = tid & 127;
        int line = line0 + l;
        int base = ((line >> 7) << 16) + ((line & 127) << 8);
        ((float4*)(s + l*256))[f4c] = ((const float4*)(W + base))[f4c];
    }
    __syncthreads();
    fft_rows2<true>(s, ltw, tid);
    {
        int l = tid >> 7, e = tid & 127;
        int line = line0 + l;
        int z = line >> 7, y = line & 127;
        cpx v = s[l*256 + e];
        const float SC2 = (1.0f/33554432.0f)*(1.0f/33554432.0f);   // (1/(512*256*256))^2
        out[(z*128 + y)*128 + e] = (v.x*v.x + v.y*v.y)*SC2;
    }
}

// ---------------- FFT along y: 256 pts = 4 radix-4 DIF stages, tile 16 x, fixed z ----------------
// Forward: store y-fftshifted AND y-half-blurred: pos e = 0.5*(F_s[e-1]+F_s[e]), F_s[-1]=0.
// Inverse: plain store, crop y<128.
template<bool INV, bool HALF_IN, bool HALF_OUT>
__global__ __launch_bounds__(1024) void k_fft_y(cpx* __restrict__ V){
    __shared__ cpx s[256*16];                   // 32 KiB
    int tid = threadIdx.x;
    int z  = blockIdx.x >> 4;
    int x0 = (blockIdx.x & 15) << 4;
    int base = (z << 16) + x0;
    const int YIN = HALF_IN ? 128 : 256;
    for (int i = tid; i < YIN*8; i += 1024){     // float4: 8 units of 2 cpx per row
        int f4c = i & 7, e = i >> 3;
        ((float4*)(s + e*16))[f4c] = ((const float4*)(V + base + (e << 8)))[f4c];
    }
    if (HALF_IN){
        for (int i = tid; i < 128*16; i += 1024){
            int c = i & 15, e = (i >> 4) + 128;
            s[e*16 + c] = make_float2(0.0f, 0.0f);
        }
    }
    __syncthreads();
    int c = tid & 15, idx = tid >> 4;
    cpx x[4];
    {   // stage 0: stride 64, tw W_512^{2*j*r}
        int j = idx;
        #pragma unroll
        for (int t = 0; t < 4; ++t) x[t] = s[(j + (t << 6))*16 + c];
        dft4<INV>(x);
        #pragma unroll
        for (int r = 1; r < 4; ++r) x[r] = twmul<INV>(x[r], 2*j*r);
        #pragma unroll
        for (int r = 0; r < 4; ++r) s[(j + (r << 6))*16 + c] = x[r];
    }
    __syncthreads();
    {   // stage 1: stride 16, tw W_512^{8*j*r}
        int j = idx & 15, g = (idx >> 4) << 6;
        #pragma unroll
        for (int t = 0; t < 4; ++t) x[t] = s[(g + j + (t << 4))*16 + c];
        dft4<INV>(x);
        #pragma unroll
        for (int r = 1; r < 4; ++r) x[r] = twmul<INV>(x[r], 8*j*r);
        #pragma unroll
        for (int r = 0; r < 4; ++r) s[(g + j + (r << 4))*16 + c] = x[r];
    }
    __syncthreads();
    {   // stage 2: stride 4, tw W_512^{32*j*r}
        int j = idx & 3, g = (idx >> 2) << 4;
        #pragma unroll
        for (int t = 0; t < 4; ++t) x[t] = s[(g + j + (t << 2))*16 + c];
        dft4<INV>(x);
        #pragma unroll
        for (int r = 1; r < 4; ++r) x[r] = twmul<INV>(x[r], 32*j*r);
        #pragma unroll
        for (int r = 0; r < 4; ++r) s[(g + j + (r << 2))*16 + c] = x[r];
    }
    __syncthreads();
    {   // stage 3: stride 1, no twiddle
        int g = idx << 2;
        #pragma unroll
        for (int t = 0; t < 4; ++t) x[t] = s[(g + t)*16 + c];
        dft4<INV>(x);
        #pragma unroll
        for (int r = 0; r < 4; ++r) s[(g + r)*16 + c] = x[r];
    }
    __syncthreads();
    const int YOUT = HALF_OUT ? 128 : 256;
    for (int i = tid; i < YOUT*8; i += 1024){
        int f4c = i & 7, e = i >> 3;
        if (!INV){
            // blurred shifted store: pos e = 0.5*(F_s[e-1] + F_s[e]); F_s[q] at row rev4(q)^2
            int p0 = (((e & 3) << 6) | (((e >> 2) & 3) << 4) | (((e >> 4) & 3) << 2) | (e >> 6)) ^ 2;
            float4 S0 = ((const float4*)(s + p0*16))[f4c];
            float4 S1 = make_float4(0.0f, 0.0f, 0.0f, 0.0f);
            if (e){
                int em = e - 1;
                int p1 = (((em & 3) << 6) | (((em >> 2) & 3) << 4) | (((em >> 4) & 3) << 2) | (em >> 6)) ^ 2;
                S1 = ((const float4*)(s + p1*16))[f4c];
            }
            float4 o;
            o.x = 0.5f*(S0.x + S1.x); o.y = 0.5f*(S0.y + S1.y);
            o.z = 0.5f*(S0.z + S1.z); o.w = 0.5f*(S0.w + S1.w);
            ((float4*)(V + base + (e << 8)))[f4c] = o;
        } else {
            int p = ((e & 3) << 6) | (((e >> 2) & 3) << 4) | (((e >> 4) & 3) << 2) | (e >> 6);
            ((float4*)(V + base + (e << 8)))[f4c] = ((const float4*)(s + p*16))[f4c];
        }
    }
}

// ---------------- FUSED z-stage: fwd FFT + Stolt gather + inverse FFT, paired columns ----------------
// Block handles columns A=(yA, x0A..+15), B=(yA+128, (x0A+128)&255 ..+15). Dest A gathers
// from B's fwd spectrum and vice versa (exact involution; lane c maps to lane c).
// Reads/writes planes 0..255 only; the z-spectrum lives entirely in LDS (128 KiB).
__global__ __launch_bounds__(1024) void k_fftz_pair(cpx* __restrict__ V){
    __shared__ cpx bufA[512*16];                // 64 KiB
    __shared__ cpx bufB[512*16];                // 64 KiB
    int tid = threadIdx.x;
    int yA  = blockIdx.x >> 4;                  // 0..127
    int x0A = (blockIdx.x & 15) << 4;
    int yB  = yA + 128;
    int x0B = (x0A + 128) & 255;
    int baseA = (yA << 8) + x0A;
    int baseB = (yB << 8) + x0B;
    // load planes 0..255 of both columns, zero-pad upper half
    for (int i = tid; i < 256*8; i += 1024){
        int f4c = i & 7, e = i >> 3;
        ((float4*)(bufA + e*16))[f4c] = ((const float4*)(V + baseA + (e << 16)))[f4c];
        ((float4*)(bufB + e*16))[f4c] = ((const float4*)(V + baseB + (e << 16)))[f4c];
    }
    for (int i = tid; i < 256*16; i += 1024){
        int cc = i & 15, e = (i >> 4) + 256;
        bufA[e*16 + cc] = make_float2(0.0f, 0.0f);
        bufB[e*16 + cc] = make_float2(0.0f, 0.0f);
    }
    __syncthreads();
    int c = tid & 15, idx = tid >> 4;
    // forward 512-pt FFTs (output left digit-reversed in LDS)
    zstage<false,0>(bufA, c, idx); zstage<false,0>(bufB, c, idx); __syncthreads();
    zstage<false,1>(bufA, c, idx); zstage<false,1>(bufB, c, idx); __syncthreads();
    zstage<false,2>(bufA, c, idx); zstage<false,2>(bufB, c, idx); __syncthreads();
    // Stolt gather: dest A's source coords are (yB, x0B+c); dest B's are (yA, x0A+c)
    float gxA = (float)(x0B + c - 128)*(1.0f/128.0f);
    float gyA = (float)(yB - 128)*(1.0f/128.0f);
    float rxyA = 0.1024f*(gxA*gxA + gyA*gyA);
    float gxB = (float)(x0A + c - 128)*(1.0f/128.0f);
    float gyB = (float)(yA - 128)*(1.0f/128.0f);
    float rxyB = 0.1024f*(gxB*gxB + gyB*gyB);
    cpx rA[4], rB[4];
    #pragma unroll
    for (int k = 0; k < 4; ++k){
        int zd = idx + (k << 6);
        rA[k] = zgather(bufB, zd, rxyA, c);
        rB[k] = zgather(bufA, zd, rxyB, c);
    }
    __syncthreads();
    #pragma unroll
    for (int k = 0; k < 4; ++k){
        int zd = idx + (k << 6);
        bufA[zd*16 + c] = rA[k];
        bufB[zd*16 + c] = rB[k];
    }
    for (int i = tid; i < 256*16; i += 1024){
        int cc = i & 15, e = (i >> 4) + 256;
        bufA[e*16 + cc] = make_float2(0.0f, 0.0f);
        bufB[e*16 + cc] = make_float2(0.0f, 0.0f);
    }
    __syncthreads();
    // inverse 512-pt FFTs
    zstage<true,0>(bufA, c, idx); zstage<true,0>(bufB, c, idx); __syncthreads();
    zstage<true,1>(bufA, c, idx); zstage<true,1>(bufB, c, idx); __syncthreads();
    zstage<true,2>(bufA, c, idx); zstage<true,2>(bufB, c, idx); __syncthreads();
    // write planes 0..255 (digit-reversal resolved at store)
    for (int i = tid; i < 256*8; i += 1024){
        int f4c = i & 7, e = i >> 3;
        int p = ((e & 7) << 6) | (e & 56) | (e >> 6);
        ((float4*)(V + baseA + (e << 16)))[f4c] = ((const float4*)(bufA + p*16))[f4c];
        ((float4*)(V + baseB + (e << 16)))[f4c] = ((const float4*)(bufB + p*16))[f4c];
    }
}

extern "C" void kernel_launch(void* const* d_in, const int* in_sizes, int n_in,
                              void* d_out, int out_size, void* d_ws, size_t ws_size,
                              hipStream_t stream){
    const float* feat = (const float*)d_in[0];   // [1,1,256,128,128] f32; tbes=0, tens=256
    float* out = (float*)d_out;                  // [1,1,256,128,128] f32

    const size_t WS_NEED = (size_t)512*256*256*8;   // 268,435,456 B exactly
    if (ws_size < WS_NEED){
        hipMemsetAsync(d_out, 0, (size_t)out_size*sizeof(float), stream);
        return;
    }
    cpx* V = (cpx*)d_ws;

    k_tw<<<1, 512, 0, stream>>>();
    // forward x (+fill,+x-blur) and y (+y-blur), stored fftshifted, planes 0..255
    k_fft_x_fill<<<16384, 256, 0, stream>>>(feat, V);               // lines z<256,y<128
    k_fft_y<false, true, false><<<4096, 1024, 0, stream>>>(V);      // z<256; y<128 in, full blurred y out
    // fused z-stage: fwd FFT + Stolt + inv FFT, paired columns, planes 0..255 in/out
    k_fftz_pair<<<2048, 1024, 0, stream>>>(V);
    // inverse y + inverse x (+|.|^2) with crops
    k_fft_y<true, false, true><<<4096, 1024, 0, stream>>>(V);       // full y in, y<128 out
    k_fft_x_inv_mag<<<16384, 256, 0, stream>>>(V, out);             // full x in, |.|^2, x<128
}